// Round 1
// baseline (5862.214 us; speedup 1.0000x reference)
//
#include <hip/hip_runtime.h>
#include <hip/hip_bf16.h>

typedef unsigned int u32;
typedef unsigned short u16;
typedef unsigned long long u64;

// ---------- bf16 helpers (bit-level, fast) ----------
__device__ __forceinline__ float bflo(u32 p){ return __uint_as_float(p << 16); }
__device__ __forceinline__ float bfhi(u32 p){ return __uint_as_float(p & 0xffff0000u); }
__device__ __forceinline__ u16 f2bf(float f){
    u32 u = __float_as_uint(f);
    u32 r = (u + 0x7fffu + ((u >> 16) & 1u)) >> 16;   // round-nearest-even
    return (u16)r;
}
__device__ __forceinline__ u32 pack2(float lo, float hi){
    return (u32)f2bf(lo) | ((u32)f2bf(hi) << 16);
}
__device__ __forceinline__ float sigmoidf_(float x){ return 1.f / (1.f + __expf(-x)); }

// strides (elements)
#define SA 130   // bf16 [64][128] padded
#define SS 65    // f32  [64][64] padded
#define SD 34    // bf16 [64][32] padded
#define SH 66    // bf16 [64][64] padded (h3 half)

// ---------- cooperative global f32 -> LDS bf16 staging ----------
__device__ __forceinline__ void stage_bf16(u16* dst, int dstride,
                                           const float* __restrict__ src, int sstride,
                                           int rows, int cols, int tid){
    int total = rows * cols;
    for (int i = tid * 2; i < total; i += 512){
        int r = i / cols, c = i - r * cols;
        float2 f = *(const float2*)(src + (size_t)r * sstride + c);
        *((u32*)(dst + r * dstride + c)) = pack2(f.x, f.y);
    }
}

// ---------- generic tiled matmul: Y[64][16*CW] = act(X @ W^T + b) ----------
// X: LDS bf16 [64][sx], W: LDS bf16 [OC][sw] (OC = 16*CW), K even.
// thread tile: 4 tokens x CW cols. Writes bf16 to dst.
template<int CW, bool RELU>
__device__ __forceinline__ void mm_lds(const u16* X, int sx, const u16* W, int sw, int K,
                                       const float* __restrict__ bias, int boff,
                                       u16* dst, int sd, int doff, int tid){
    const int t0 = (tid >> 4) * 4;
    const int c0 = (tid & 15) * CW;
    float acc[4][CW];
    #pragma unroll
    for (int i = 0; i < 4; i++)
        #pragma unroll
        for (int j = 0; j < CW; j++) acc[i][j] = 0.f;
    for (int k = 0; k < K; k += 2){
        float al[4], ah[4];
        #pragma unroll
        for (int i = 0; i < 4; i++){
            u32 p = *(const u32*)(X + (t0 + i) * sx + k);
            al[i] = bflo(p); ah[i] = bfhi(p);
        }
        #pragma unroll
        for (int j = 0; j < CW; j++){
            u32 p = *(const u32*)(W + (c0 + j) * sw + k);
            float bl = bflo(p), bh = bfhi(p);
            #pragma unroll
            for (int i = 0; i < 4; i++) acc[i][j] += al[i] * bl + ah[i] * bh;
        }
    }
    #pragma unroll
    for (int j = 0; j < CW; j++){
        float bv = bias[boff + c0 + j];
        #pragma unroll
        for (int i = 0; i < 4; i++){
            float v = acc[i][j] + bv;
            if (RELU) v = fmaxf(v, 0.f);
            dst[(t0 + i) * sd + doff + c0 + j] = f2bf(v);
        }
    }
}

// matmul into registers (no bias, no store): acc[4][4], OC=64 slice
__device__ __forceinline__ void mm_regs(const u16* X, int sx, const u16* W, int sw, int K,
                                        float acc[4][4], int tid){
    const int t0 = (tid >> 4) * 4;
    const int c0 = (tid & 15) * 4;
    #pragma unroll
    for (int i = 0; i < 4; i++)
        #pragma unroll
        for (int j = 0; j < 4; j++) acc[i][j] = 0.f;
    for (int k = 0; k < K; k += 2){
        float al[4], ah[4];
        #pragma unroll
        for (int i = 0; i < 4; i++){
            u32 p = *(const u32*)(X + (t0 + i) * sx + k);
            al[i] = bflo(p); ah[i] = bfhi(p);
        }
        #pragma unroll
        for (int j = 0; j < 4; j++){
            u32 p = *(const u32*)(W + (c0 + j) * sw + k);
            float bl = bflo(p), bh = bfhi(p);
            #pragma unroll
            for (int i = 0; i < 4; i++) acc[i][j] += al[i] * bl + ah[i] * bh;
        }
    }
}

__global__ __launch_bounds__(256) void drgn_fused(
    const float* __restrict__ x, const int* __restrict__ mask, const float* __restrict__ h0,
    const float* __restrict__ enc_w, const float* __restrict__ enc_b,
    const float* __restrict__ q1_w, const float* __restrict__ q1_b,
    const float* __restrict__ k1_w, const float* __restrict__ k1_b,
    const float* __restrict__ v1_w, const float* __restrict__ v1_b,
    const float* __restrict__ o1_w, const float* __restrict__ o1_b,
    const float* __restrict__ q2_w, const float* __restrict__ q2_b,
    const float* __restrict__ k2_w, const float* __restrict__ k2_b,
    const float* __restrict__ v2_w, const float* __restrict__ v2_b,
    const float* __restrict__ o2_w, const float* __restrict__ o2_b,
    const float* __restrict__ gwih, const float* __restrict__ gwhh,
    const float* __restrict__ gbih, const float* __restrict__ gbhh,
    const float* __restrict__ lin_w, const float* __restrict__ lin_b,
    float* __restrict__ out_qs, float* __restrict__ out_h3)
{
    const int b = blockIdx.x;
    const int tid = threadIdx.x;
    const int t0 = (tid >> 4) * 4;

    __shared__ __align__(16) u16 Xs[64 * SA];        // 16640 B: activations
    __shared__ __align__(16) u16 Bs[64 * SA];        // 16640 B: x / attn-out / h0
    __shared__ __align__(16) u32 WSS[64 * 65];       // 16640 B union: W bf16 [64][SA] | scores f32 [64][SS] | mask u32
    __shared__ __align__(16) u16 Ds[3 * 64 * SD];    // 13056 B: q_h,k_h,v_h | h3-half [64][SH]

    u16*   Ws = (u16*)WSS;
    float* Ss = (float*)WSS;

    // ---- load mask, pack per-thread row bits; stage x -> Bs ----
    {
        const int4* mb = (const int4*)(mask + (size_t)b * 4096);
        #pragma unroll
        for (int rep = 0; rep < 4; rep++)
            ((int4*)WSS)[tid + rep * 256] = mb[tid + rep * 256];
    }
    __syncthreads();
    u64 mbits[4];
    #pragma unroll
    for (int i = 0; i < 4; i++){
        u64 m = 0;
        for (int j = 0; j < 64; j++) m |= (u64)(WSS[(t0 + i) * 64 + j] != 0u) << j;
        mbits[i] = m;
    }
    stage_bf16(Bs, SA, x + (size_t)b * 64 * 64, 64, 64, 64, tid);
    __syncthreads();

    // ---- encoder: Xs = relu(Bs @ enc_w^T + enc_b), K=64, 2 col-halves ----
    for (int half = 0; half < 2; half++){
        stage_bf16(Ws, SA, enc_w + (size_t)half * 64 * 64, 64, 64, 64, tid);
        __syncthreads();
        mm_lds<4, true>(Bs, SA, Ws, SA, 64, enc_b, half * 64, Xs, SA, half * 64, tid);
        __syncthreads();
    }

    // ---- two MHA layers ----
    const float* WQ[2] = {q1_w, q2_w}; const float* BQ[2] = {q1_b, q2_b};
    const float* WK[2] = {k1_w, k2_w}; const float* BK[2] = {k1_b, k2_b};
    const float* WV[2] = {v1_w, v2_w}; const float* BV[2] = {v1_b, v2_b};
    const float* WO[2] = {o1_w, o2_w}; const float* BO[2] = {o1_b, o2_b};

    for (int layer = 0; layer < 2; layer++){
        for (int h = 0; h < 4; h++){
            u16* Qh = Ds;
            u16* Kh = Ds + 64 * SD;
            u16* Vh = Ds + 2 * 64 * SD;
            // q_h, k_h, v_h projections (OC=32, K=128, relu)
            stage_bf16(Ws, SA, WQ[layer] + (size_t)h * 32 * 128, 128, 32, 128, tid); __syncthreads();
            mm_lds<2, true>(Xs, SA, Ws, SA, 128, BQ[layer], h * 32, Qh, SD, 0, tid); __syncthreads();
            stage_bf16(Ws, SA, WK[layer] + (size_t)h * 32 * 128, 128, 32, 128, tid); __syncthreads();
            mm_lds<2, true>(Xs, SA, Ws, SA, 128, BK[layer], h * 32, Kh, SD, 0, tid); __syncthreads();
            stage_bf16(Ws, SA, WV[layer] + (size_t)h * 32 * 128, 128, 32, 128, tid); __syncthreads();
            mm_lds<2, true>(Xs, SA, Ws, SA, 128, BV[layer], h * 32, Vh, SD, 0, tid); __syncthreads();

            // scores: Ss[q][m] = mask ? (q.k)/sqrt(32) : -NEG   (overwrites Ws region)
            {
                const int m0 = (tid & 15) * 4;
                float s[4][4];
                #pragma unroll
                for (int i = 0; i < 4; i++)
                    #pragma unroll
                    for (int j = 0; j < 4; j++) s[i][j] = 0.f;
                for (int d = 0; d < 32; d += 2){
                    float ql[4], qh[4];
                    #pragma unroll
                    for (int i = 0; i < 4; i++){
                        u32 p = *(const u32*)(Qh + (t0 + i) * SD + d);
                        ql[i] = bflo(p); qh[i] = bfhi(p);
                    }
                    #pragma unroll
                    for (int j = 0; j < 4; j++){
                        u32 p = *(const u32*)(Kh + (m0 + j) * SD + d);
                        float kl = bflo(p), kh2 = bfhi(p);
                        #pragma unroll
                        for (int i = 0; i < 4; i++) s[i][j] += ql[i] * kl + qh[i] * kh2;
                    }
                }
                #pragma unroll
                for (int i = 0; i < 4; i++)
                    #pragma unroll
                    for (int j = 0; j < 4; j++){
                        bool on = (mbits[i] >> (m0 + j)) & 1ull;
                        Ss[(t0 + i) * SS + m0 + j] = on ? s[i][j] * 0.17677669529663687f
                                                        : -9.0e15f;
                    }
            }
            __syncthreads();

            // softmax over m (4 lanes per row, shuffle reduce)
            {
                const int r = tid >> 2, seg = tid & 3;
                float* row = Ss + r * SS + seg * 16;
                float mx = row[0];
                #pragma unroll
                for (int i = 1; i < 16; i++) mx = fmaxf(mx, row[i]);
                mx = fmaxf(mx, __shfl_xor(mx, 1));
                mx = fmaxf(mx, __shfl_xor(mx, 2));
                float e[16], sum = 0.f;
                #pragma unroll
                for (int i = 0; i < 16; i++){ e[i] = __expf(row[i] - mx); sum += e[i]; }
                sum += __shfl_xor(sum, 1);
                sum += __shfl_xor(sum, 2);
                float inv = 1.f / sum;
                #pragma unroll
                for (int i = 0; i < 16; i++) row[i] = e[i] * inv;
            }
            __syncthreads();

            // PV: Bs[:, h*32 + d] = P @ v_h   (thread tile 4 tok x 2 d)
            {
                const int d0 = (tid & 15) * 2;
                float o[4][2];
                #pragma unroll
                for (int i = 0; i < 4; i++){ o[i][0] = 0.f; o[i][1] = 0.f; }
                for (int m = 0; m < 64; m++){
                    u32 vv = *(const u32*)(Vh + m * SD + d0);
                    float v0 = bflo(vv), v1 = bfhi(vv);
                    #pragma unroll
                    for (int i = 0; i < 4; i++){
                        float p = Ss[(t0 + i) * SS + m];
                        o[i][0] += p * v0;
                        o[i][1] += p * v1;
                    }
                }
                #pragma unroll
                for (int i = 0; i < 4; i++){
                    Bs[(t0 + i) * SA + h * 32 + d0 + 0] = f2bf(o[i][0]);
                    Bs[(t0 + i) * SA + h * 32 + d0 + 1] = f2bf(o[i][1]);
                }
            }
            __syncthreads();
        }
        // o-proj: Xs = relu(Bs @ o_w^T + o_b)
        for (int half = 0; half < 2; half++){
            stage_bf16(Ws, SA, WO[layer] + (size_t)half * 64 * 128, 128, 64, 128, tid);
            __syncthreads();
            mm_lds<4, true>(Bs, SA, Ws, SA, 128, BO[layer], half * 64, Xs, SA, half * 64, tid);
            __syncthreads();
        }
    }

    // ---- GRU + final linear ----
    stage_bf16(Bs, SA, h0 + (size_t)b * 64 * 128, 128, 64, 128, tid);  // h0 bf16 for matmuls
    __syncthreads();

    const int c0 = (tid & 15) * 4;
    float qacc[5] = {0.f, 0.f, 0.f, 0.f, 0.f};

    for (int half = 0; half < 2; half++){
        float accI[4][4], accH[4][4], rr[4][4], zz[4][4];

        // r gate
        stage_bf16(Ws, SA, gwih + (size_t)(0 * 128 + half * 64) * 128, 128, 64, 128, tid); __syncthreads();
        mm_regs(Xs, SA, Ws, SA, 128, accI, tid); __syncthreads();
        stage_bf16(Ws, SA, gwhh + (size_t)(0 * 128 + half * 64) * 128, 128, 64, 128, tid); __syncthreads();
        mm_regs(Bs, SA, Ws, SA, 128, accH, tid); __syncthreads();
        #pragma unroll
        for (int j = 0; j < 4; j++){
            float bi = gbih[0 * 128 + half * 64 + c0 + j], bh = gbhh[0 * 128 + half * 64 + c0 + j];
            #pragma unroll
            for (int i = 0; i < 4; i++) rr[i][j] = sigmoidf_(accI[i][j] + bi + accH[i][j] + bh);
        }
        // z gate
        stage_bf16(Ws, SA, gwih + (size_t)(1 * 128 + half * 64) * 128, 128, 64, 128, tid); __syncthreads();
        mm_regs(Xs, SA, Ws, SA, 128, accI, tid); __syncthreads();
        stage_bf16(Ws, SA, gwhh + (size_t)(1 * 128 + half * 64) * 128, 128, 64, 128, tid); __syncthreads();
        mm_regs(Bs, SA, Ws, SA, 128, accH, tid); __syncthreads();
        #pragma unroll
        for (int j = 0; j < 4; j++){
            float bi = gbih[1 * 128 + half * 64 + c0 + j], bh = gbhh[1 * 128 + half * 64 + c0 + j];
            #pragma unroll
            for (int i = 0; i < 4; i++) zz[i][j] = sigmoidf_(accI[i][j] + bi + accH[i][j] + bh);
        }
        // n gate
        stage_bf16(Ws, SA, gwih + (size_t)(2 * 128 + half * 64) * 128, 128, 64, 128, tid); __syncthreads();
        mm_regs(Xs, SA, Ws, SA, 128, accI, tid); __syncthreads();
        stage_bf16(Ws, SA, gwhh + (size_t)(2 * 128 + half * 64) * 128, 128, 64, 128, tid); __syncthreads();
        mm_regs(Bs, SA, Ws, SA, 128, accH, tid); __syncthreads();

        // combine + write h3 (f32 h0 from global for accuracy)
        #pragma unroll
        for (int j = 0; j < 4; j++){
            float bi = gbih[2 * 128 + half * 64 + c0 + j], bh = gbhh[2 * 128 + half * 64 + c0 + j];
            #pragma unroll
            for (int i = 0; i < 4; i++){
                float n  = tanhf(accI[i][j] + bi + rr[i][j] * (accH[i][j] + bh));
                float hv = h0[((size_t)b * 64 + t0 + i) * 128 + half * 64 + c0 + j];
                float h3 = (1.f - zz[i][j]) * n + zz[i][j] * hv;
                out_h3[((size_t)b * 64 + t0 + i) * 128 + half * 64 + c0 + j] = h3;
                Ds[(t0 + i) * SH + c0 + j] = f2bf(h3);   // h3 half-slab for qs
            }
        }
        __syncthreads();

        // qs partial: += h3_half @ lin_w[:, half*64:half*64+64]^T
        stage_bf16(Ws, SA, lin_w + half * 64, 128, 20, 64, tid);
        __syncthreads();
        #pragma unroll
        for (int rep = 0; rep < 5; rep++){
            int o = tid + rep * 256;
            int tok = o / 20, j = o - tok * 20;
            float a = 0.f;
            for (int k = 0; k < 64; k += 2){
                u32 hp = *(const u32*)(Ds + tok * SH + k);
                u32 wp = *(const u32*)(Ws + j * SA + k);
                a += bflo(hp) * bflo(wp) + bfhi(hp) * bfhi(wp);
            }
            qacc[rep] += a;
        }
        __syncthreads();
    }

    #pragma unroll
    for (int rep = 0; rep < 5; rep++){
        int o = tid + rep * 256;
        out_qs[(size_t)b * 1280 + o] = qacc[rep] + lin_b[o - (o / 20) * 20];
    }
}

extern "C" void kernel_launch(void* const* d_in, const int* in_sizes, int n_in,
                              void* d_out, int out_size, void* d_ws, size_t ws_size,
                              hipStream_t stream) {
    const float* x     = (const float*)d_in[0];
    const int*   mask  = (const int*)  d_in[1];
    const float* h0    = (const float*)d_in[2];
    const float* enc_w = (const float*)d_in[3];
    const float* enc_b = (const float*)d_in[4];
    const float* q1_w  = (const float*)d_in[5];  const float* q1_b = (const float*)d_in[6];
    const float* k1_w  = (const float*)d_in[7];  const float* k1_b = (const float*)d_in[8];
    const float* v1_w  = (const float*)d_in[9];  const float* v1_b = (const float*)d_in[10];
    const float* o1_w  = (const float*)d_in[11]; const float* o1_b = (const float*)d_in[12];
    const float* q2_w  = (const float*)d_in[13]; const float* q2_b = (const float*)d_in[14];
    const float* k2_w  = (const float*)d_in[15]; const float* k2_b = (const float*)d_in[16];
    const float* v2_w  = (const float*)d_in[17]; const float* v2_b = (const float*)d_in[18];
    const float* o2_w  = (const float*)d_in[19]; const float* o2_b = (const float*)d_in[20];
    const float* gwih  = (const float*)d_in[21]; const float* gwhh = (const float*)d_in[22];
    const float* gbih  = (const float*)d_in[23]; const float* gbhh = (const float*)d_in[24];
    const float* lin_w = (const float*)d_in[25]; const float* lin_b = (const float*)d_in[26];

    const int bs = in_sizes[0] / (64 * 64);           // 4096
    float* out_qs = (float*)d_out;
    float* out_h3 = out_qs + (size_t)bs * 64 * 20;

    hipLaunchKernelGGL(drgn_fused, dim3(bs), dim3(256), 0, stream,
                       x, mask, h0, enc_w, enc_b,
                       q1_w, q1_b, k1_w, k1_b, v1_w, v1_b, o1_w, o1_b,
                       q2_w, q2_b, k2_w, k2_b, v2_w, v2_b, o2_w, o2_b,
                       gwih, gwhh, gbih, gbhh, lin_w, lin_b,
                       out_qs, out_h3);
}

// Round 2
// 600.943 us; speedup vs baseline: 9.7550x; 9.7550x over previous
//
#include <hip/hip_runtime.h>
#include <hip/hip_bf16.h>

typedef unsigned int u32;
typedef unsigned short u16;
typedef unsigned long long u64;

using bf16x8 = __attribute__((ext_vector_type(8))) short;
using f32x4  = __attribute__((ext_vector_type(4))) float;

// ---------- bf16 helpers ----------
__device__ __forceinline__ u16 f2bf(float f){
    u32 u = __float_as_uint(f);
    u32 r = (u + 0x7fffu + ((u >> 16) & 1u)) >> 16;   // RNE
    return (u16)r;
}
__device__ __forceinline__ u32 pack2(float lo, float hi){
    return (u32)f2bf(lo) | ((u32)f2bf(hi) << 16);
}

// LDS strides (elements)
#define SX  136   // activations [128][128] bf16 (272B rows, 16B aligned, 2-way banks)
#define SIN 72    // x input [128][64] bf16
#define SQK 40    // Q/K per-head [128][32] bf16 (80B rows)
#define SVT 136   // V transposed [32][128] bf16
#define SSC 68    // scores f32 [128][64]
#define SP  72    // P bf16 [128][64]

// ws (bf16 weights) offsets, elements
#define OFF_ENC 0
#define OFF_ATT 8192
#define OFF_GIH 139264
#define OFF_GHH 188416
#define OFF_LIN 237568
#define W16_TOTAL 241664

// ---------- weight f32 -> bf16 pre-conversion ----------
__global__ __launch_bounds__(256) void convert_weights(
    const float* __restrict__ enc, const float* __restrict__ q1, const float* __restrict__ k1,
    const float* __restrict__ v1, const float* __restrict__ o1,
    const float* __restrict__ q2, const float* __restrict__ k2, const float* __restrict__ v2,
    const float* __restrict__ o2, const float* __restrict__ gih, const float* __restrict__ ghh,
    const float* __restrict__ lin, u16* __restrict__ dst)
{
    int idx = blockIdx.x * 256 + threadIdx.x;
    if (idx >= W16_TOTAL) return;
    float v;
    if (idx >= OFF_LIN){
        int i = idx - OFF_LIN;                 // [32][128], rows 20..31 zero-padded
        v = (i < 2560) ? lin[i] : 0.f;
    } else {
        const float* s; int base;
        if      (idx <   8192){ s = enc; base = 0; }
        else if (idx <  24576){ s = q1;  base = 8192; }
        else if (idx <  40960){ s = k1;  base = 24576; }
        else if (idx <  57344){ s = v1;  base = 40960; }
        else if (idx <  73728){ s = o1;  base = 57344; }
        else if (idx <  90112){ s = q2;  base = 73728; }
        else if (idx < 106496){ s = k2;  base = 90112; }
        else if (idx < 122880){ s = v2;  base = 106496; }
        else if (idx < OFF_GIH){ s = o2; base = 122880; }
        else if (idx < OFF_GHH){ s = gih; base = OFF_GIH; }
        else                  { s = ghh; base = OFF_GHH; }
        v = s[idx - base];
    }
    dst[idx] = f2bf(v);
}

// ---------- staging helpers (512 threads) ----------
// bf16 [oc][K] global -> LDS [oc][sd], KCL = log2(K/8)
template<int KCL>
__device__ __forceinline__ void stage_w(u16* dst, int sd, const u16* __restrict__ src,
                                        int oc, int tid){
    const int total = oc << KCL;
    for (int ch = tid; ch < total; ch += 512){
        int row = ch >> KCL, cp = ch - (row << KCL);
        *(bf16x8*)(dst + row * sd + cp * 8) =
            *(const bf16x8*)(src + ((size_t)row << (KCL + 3)) + cp * 8);
    }
}
// f32 [rows][C] global -> LDS bf16 [rows][sd], CSH = log2(C/8)
template<int CSH>
__device__ __forceinline__ void stage_f32(u16* dst, int sd, const float* __restrict__ src,
                                          int tid, int total){
    for (int ch = tid; ch < total; ch += 512){
        int row = ch >> CSH, cp = ch - (row << CSH);
        const float* sp = src + ((size_t)row << (CSH + 3)) + cp * 8;
        float4 f0 = *(const float4*)(sp);
        float4 f1 = *(const float4*)(sp + 4);
        u32* dp = (u32*)(dst + row * sd + cp * 8);
        dp[0] = pack2(f0.x, f0.y); dp[1] = pack2(f0.z, f0.w);
        dp[2] = pack2(f1.x, f1.y); dp[3] = pack2(f1.z, f1.w);
    }
}

// ---------- MFMA GEMM core: M=128 (8 tiles), wave w owns 2 M-tiles x NTW N-tiles ----------
template<int NTW>
__device__ __forceinline__ void zacc(f32x4 acc[2][NTW]){
    #pragma unroll
    for (int i = 0; i < 2; i++)
        #pragma unroll
        for (int j = 0; j < NTW; j++) acc[i][j] = (f32x4){0.f, 0.f, 0.f, 0.f};
}

template<int NTW, int KK>
__device__ __forceinline__ void gemm_core(const u16* A, int sa, const u16* B, int sb,
                                          int w, int lane, f32x4 acc[2][NTW]){
    const int mtb = (w >> 1) * 2;
    const int ntb = (w & 1) * NTW;
    const int c = lane & 15, g = lane >> 4;
    #pragma unroll
    for (int kk = 0; kk < KK; kk++){
        bf16x8 a[2];
        #pragma unroll
        for (int i = 0; i < 2; i++)
            a[i] = *(const bf16x8*)(A + ((mtb + i) * 16 + c) * sa + kk * 32 + g * 8);
        #pragma unroll
        for (int j = 0; j < NTW; j++){
            bf16x8 bf = *(const bf16x8*)(B + ((ntb + j) * 16 + c) * sb + kk * 32 + g * 8);
            #pragma unroll
            for (int i = 0; i < 2; i++)
                acc[i][j] = __builtin_amdgcn_mfma_f32_16x16x32_bf16(a[i], bf, acc[i][j], 0, 0, 0);
        }
    }
}

template<int NTW, bool RELU>
__device__ __forceinline__ void epi_row(f32x4 acc[2][NTW], const float* __restrict__ bias, int boff,
                                        u16* dst, int sd, int doff, int w, int lane){
    const int mtb = (w >> 1) * 2, ntb = (w & 1) * NTW;
    const int c = lane & 15, g = lane >> 4;
    #pragma unroll
    for (int j = 0; j < NTW; j++){
        const int col = (ntb + j) * 16 + c;
        const float bv = bias[boff + col];
        #pragma unroll
        for (int i = 0; i < 2; i++)
            #pragma unroll
            for (int r = 0; r < 4; r++){
                float v = acc[i][j][r] + bv;
                if (RELU) v = fmaxf(v, 0.f);
                dst[((mtb + i) * 16 + g * 4 + r) * sd + doff + col] = f2bf(v);
            }
    }
}

// ---------- main fused kernel: 2 batch items per block, 512 threads ----------
__global__ __launch_bounds__(512, 2) void drgn_mfma(
    const float* __restrict__ x, const int* __restrict__ maskg, const float* __restrict__ h0,
    const u16* __restrict__ W16,
    const float* __restrict__ enc_b,
    const float* __restrict__ q1_b, const float* __restrict__ k1_b,
    const float* __restrict__ v1_b, const float* __restrict__ o1_b,
    const float* __restrict__ q2_b, const float* __restrict__ k2_b,
    const float* __restrict__ v2_b, const float* __restrict__ o2_b,
    const float* __restrict__ gbih, const float* __restrict__ gbhh,
    const float* __restrict__ lin_b,
    float* __restrict__ out_qs, float* __restrict__ out_h3)
{
    __shared__ __align__(16) u16 X0[128 * SX];    // 34816 B
    __shared__ __align__(16) u16 X1[128 * SX];    // 34816 B
    __shared__ __align__(16) u16 WT[128 * SX];    // 34816 B (union: scores f32 [128][68])
    __shared__ __align__(16) u16 Dd[14592];       // 29184 B (union: x-in | Qh,Kh,Vt | P | -)
    __shared__ u64 Mrow[128];

    float* Ss = (float*)WT;
    u16* Qh  = Dd;                 // [128][40]
    u16* Kh  = Dd + 5120;          // [128][40]
    u16* Vt  = Dd + 10240;         // [32][136]
    u16* Px  = Dd;                 // [128][72] (overlays Qh+Kh)
    u16* Xin = Dd;                 // [128][72]

    const int tid  = threadIdx.x;
    const int w    = tid >> 6, lane = tid & 63;
    const int c    = lane & 15, g = lane >> 4;
    const int b2   = blockIdx.x;
    const size_t rowbase = (size_t)b2 * 128;

    // mask -> per-row u64 bitmask (each wave packs 16 rows, coalesced 256B reads)
    for (int rr = 0; rr < 16; rr++){
        int row = w * 16 + rr;
        int mv = maskg[(rowbase + row) * 64 + lane];
        u64 bits = __ballot(mv != 0);
        if (lane == 0) Mrow[row] = bits;
    }
    // x [128][64] f32 -> Xin bf16
    stage_f32<3>(Xin, SIN, x + rowbase * 64, tid, 1024);
    __syncthreads();

    // ---- encoder: X0 = relu(Xin @ enc_w^T + enc_b), K=64 ----
    stage_w<3>(WT, SIN, W16 + OFF_ENC, 128, tid);
    __syncthreads();
    {
        f32x4 acc[2][4]; zacc<4>(acc);
        gemm_core<4, 2>(Xin, SIN, WT, SIN, w, lane, acc);
        epi_row<4, true>(acc, enc_b, 0, X0, SX, 0, w, lane);
    }
    __syncthreads();

    // ---- two MHA layers ----
    for (int layer = 0; layer < 2; layer++){
        const u16* wq = W16 + OFF_ATT + layer * 65536;
        const u16* wk = wq + 16384;
        const u16* wv = wq + 32768;
        const u16* wo = wq + 49152;
        const float* qb = layer ? q2_b : q1_b;
        const float* kb = layer ? k2_b : k1_b;
        const float* vb = layer ? v2_b : v1_b;
        const float* ob = layer ? o2_b : o1_b;

        for (int h = 0; h < 4; h++){
            // Q_h = relu(X0 @ wq_h^T + b) -> Qh [128][32]
            stage_w<4>(WT, SX, wq + h * 32 * 128, 32, tid);
            __syncthreads();
            { f32x4 a[2][1]; zacc<1>(a); gemm_core<1, 4>(X0, SX, WT, SX, w, lane, a);
              epi_row<1, true>(a, qb, h * 32, Qh, SQK, 0, w, lane); }
            __syncthreads();
            // K_h
            stage_w<4>(WT, SX, wk + h * 32 * 128, 32, tid);
            __syncthreads();
            { f32x4 a[2][1]; zacc<1>(a); gemm_core<1, 4>(X0, SX, WT, SX, w, lane, a);
              epi_row<1, true>(a, kb, h * 32, Kh, SQK, 0, w, lane); }
            __syncthreads();
            // V_h -> Vt transposed [d][token]
            stage_w<4>(WT, SX, wv + h * 32 * 128, 32, tid);
            __syncthreads();
            { f32x4 a[2][1]; zacc<1>(a); gemm_core<1, 4>(X0, SX, WT, SX, w, lane, a);
              const int mtb = (w >> 1) * 2;
              const int d = (w & 1) * 16 + c;
              const float bv = vb[h * 32 + d];
              #pragma unroll
              for (int i = 0; i < 2; i++){
                  float v0 = fmaxf(a[i][0][0] + bv, 0.f);
                  float v1 = fmaxf(a[i][0][1] + bv, 0.f);
                  float v2 = fmaxf(a[i][0][2] + bv, 0.f);
                  float v3 = fmaxf(a[i][0][3] + bv, 0.f);
                  uint2 val; val.x = pack2(v0, v1); val.y = pack2(v2, v3);
                  *(uint2*)(Vt + d * SVT + (mtb + i) * 16 + g * 4) = val;
              }
            }
            __syncthreads();

            // scores: S = mask ? (Q K^T)/sqrt(32) : -1e30  (writes WT region as f32)
            {
                const int bb = w >> 2, mt = w & 3;
                bf16x8 qf = *(const bf16x8*)(Qh + (bb * 64 + mt * 16 + c) * SQK + g * 8);
                f32x4 sc[4];
                #pragma unroll
                for (int j = 0; j < 4; j++){
                    bf16x8 kf = *(const bf16x8*)(Kh + (bb * 64 + j * 16 + c) * SQK + g * 8);
                    f32x4 z = (f32x4){0.f, 0.f, 0.f, 0.f};
                    sc[j] = __builtin_amdgcn_mfma_f32_16x16x32_bf16(qf, kf, z, 0, 0, 0);
                }
                #pragma unroll
                for (int r = 0; r < 4; r++){
                    int rl = mt * 16 + g * 4 + r;
                    u64 mb = Mrow[bb * 64 + rl];
                    #pragma unroll
                    for (int j = 0; j < 4; j++){
                        int colb = j * 16 + c;
                        float sv = sc[j][r] * 0.17677669529663687f;
                        Ss[(bb * 64 + rl) * SSC + colb] = ((mb >> colb) & 1ull) ? sv : -1e30f;
                    }
                }
            }
            __syncthreads();

            // softmax rows (4 threads/row) -> P bf16
            {
                int r = tid >> 2, seg = tid & 3;
                float* rowp = Ss + r * SSC + seg * 16;
                float vals[16];
                #pragma unroll
                for (int q = 0; q < 4; q++){
                    f32x4 t = ((const f32x4*)rowp)[q];
                    vals[q*4+0] = t[0]; vals[q*4+1] = t[1]; vals[q*4+2] = t[2]; vals[q*4+3] = t[3];
                }
                float mx = vals[0];
                #pragma unroll
                for (int t = 1; t < 16; t++) mx = fmaxf(mx, vals[t]);
                mx = fmaxf(mx, __shfl_xor(mx, 1));
                mx = fmaxf(mx, __shfl_xor(mx, 2));
                float sum = 0.f;
                #pragma unroll
                for (int t = 0; t < 16; t++){ vals[t] = __expf(vals[t] - mx); sum += vals[t]; }
                sum += __shfl_xor(sum, 1);
                sum += __shfl_xor(sum, 2);
                float inv = 1.f / sum;
                u32* dp = (u32*)(Px + r * SP + seg * 16);
                #pragma unroll
                for (int t = 0; t < 8; t++) dp[t] = pack2(vals[2*t] * inv, vals[2*t+1] * inv);
            }
            __syncthreads();

            // PV: X1[:, h*32..] = P @ V
            {
                const int bb = w >> 2, mt = w & 3;
                f32x4 pa[2];
                pa[0] = (f32x4){0.f,0.f,0.f,0.f}; pa[1] = (f32x4){0.f,0.f,0.f,0.f};
                #pragma unroll
                for (int kk = 0; kk < 2; kk++){
                    bf16x8 pf = *(const bf16x8*)(Px + (bb * 64 + mt * 16 + c) * SP + kk * 32 + g * 8);
                    #pragma unroll
                    for (int nt = 0; nt < 2; nt++){
                        bf16x8 vf = *(const bf16x8*)(Vt + (nt * 16 + c) * SVT + bb * 64 + kk * 32 + g * 8);
                        pa[nt] = __builtin_amdgcn_mfma_f32_16x16x32_bf16(pf, vf, pa[nt], 0, 0, 0);
                    }
                }
                #pragma unroll
                for (int nt = 0; nt < 2; nt++)
                    #pragma unroll
                    for (int r = 0; r < 4; r++)
                        X1[(bb * 64 + mt * 16 + g * 4 + r) * SX + h * 32 + nt * 16 + c] =
                            f2bf(pa[nt][r]);
            }
            __syncthreads();
        }
        // o-proj: X0 = relu(X1 @ wo^T + ob)
        stage_w<4>(WT, SX, wo, 128, tid);
        __syncthreads();
        { f32x4 a[2][4]; zacc<4>(a); gemm_core<4, 4>(X1, SX, WT, SX, w, lane, a);
          epi_row<4, true>(a, ob, 0, X0, SX, 0, w, lane); }
        __syncthreads();
    }

    // ---- GRU ----
    stage_f32<4>(X1, SX, h0 + rowbase * 128, tid, 2048);   // h0 bf16 for matmuls
    __syncthreads();

    const u16* wih = W16 + OFF_GIH;
    const u16* whh = W16 + OFF_GHH;
    const int mtb = (w >> 1) * 2, ntb = (w & 1) * 4;

    f32x4 aI[2][4], aH[2][4];
    float rz[2][2][4][4];

    #pragma unroll
    for (int gate = 0; gate < 2; gate++){            // 0=r, 1=z
        stage_w<4>(WT, SX, wih + gate * 16384, 128, tid); __syncthreads();
        zacc<4>(aI); gemm_core<4, 4>(X0, SX, WT, SX, w, lane, aI); __syncthreads();
        stage_w<4>(WT, SX, whh + gate * 16384, 128, tid); __syncthreads();
        zacc<4>(aH); gemm_core<4, 4>(X1, SX, WT, SX, w, lane, aH); __syncthreads();
        #pragma unroll
        for (int j = 0; j < 4; j++){
            int col = (ntb + j) * 16 + c;
            float bi = gbih[gate * 128 + col], bh = gbhh[gate * 128 + col];
            #pragma unroll
            for (int i = 0; i < 2; i++)
                #pragma unroll
                for (int r = 0; r < 4; r++)
                    rz[gate][i][j][r] =
                        1.f / (1.f + __expf(-(aI[i][j][r] + bi + aH[i][j][r] + bh)));
        }
    }
    // n gate
    stage_w<4>(WT, SX, wih + 2 * 16384, 128, tid); __syncthreads();
    zacc<4>(aI); gemm_core<4, 4>(X0, SX, WT, SX, w, lane, aI); __syncthreads();
    stage_w<4>(WT, SX, whh + 2 * 16384, 128, tid); __syncthreads();
    zacc<4>(aH); gemm_core<4, 4>(X1, SX, WT, SX, w, lane, aH); __syncthreads();

    // combine + write h3 (f32 h0 re-read for accuracy); h3 bf16 -> X0 for lin
    #pragma unroll
    for (int j = 0; j < 4; j++){
        int col = (ntb + j) * 16 + c;
        float bi = gbih[256 + col], bh = gbhh[256 + col];
        #pragma unroll
        for (int i = 0; i < 2; i++)
            #pragma unroll
            for (int r = 0; r < 4; r++){
                float pre = aH[i][j][r] + bh;
                float xn  = aI[i][j][r] + bi + rz[0][i][j][r] * pre;
                float e2  = __expf(-2.f * fabsf(xn));
                float th  = (1.f - e2) / (1.f + e2);
                th = (xn >= 0.f) ? th : -th;
                float zv  = rz[1][i][j][r];
                size_t grow = rowbase + (mtb + i) * 16 + g * 4 + r;
                float hv  = h0[grow * 128 + col];
                float h3v = (1.f - zv) * th + zv * hv;
                out_h3[grow * 128 + col] = h3v;
                X0[((mtb + i) * 16 + g * 4 + r) * SX + col] = f2bf(h3v);
            }
    }
    __syncthreads();

    // ---- final linear: qs = h3 @ lin_w^T + lin_b (lin padded to [32][128]) ----
    stage_w<4>(WT, SX, W16 + OFF_LIN, 32, tid);
    __syncthreads();
    {
        f32x4 a[2][1]; zacc<1>(a);
        gemm_core<1, 4>(X0, SX, WT, SX, w, lane, a);
        int colq = (w & 1) * 16 + c;
        if (colq < 20){
            float bv = lin_b[colq];
            #pragma unroll
            for (int i = 0; i < 2; i++)
                #pragma unroll
                for (int r = 0; r < 4; r++)
                    out_qs[(rowbase + (mtb + i) * 16 + g * 4 + r) * 20 + colq] = a[i][0][r] + bv;
        }
    }
}

extern "C" void kernel_launch(void* const* d_in, const int* in_sizes, int n_in,
                              void* d_out, int out_size, void* d_ws, size_t ws_size,
                              hipStream_t stream) {
    const float* x     = (const float*)d_in[0];
    const int*   mask  = (const int*)  d_in[1];
    const float* h0    = (const float*)d_in[2];
    const float* enc_w = (const float*)d_in[3];
    const float* enc_b = (const float*)d_in[4];
    const float* q1_w  = (const float*)d_in[5];  const float* q1_b = (const float*)d_in[6];
    const float* k1_w  = (const float*)d_in[7];  const float* k1_b = (const float*)d_in[8];
    const float* v1_w  = (const float*)d_in[9];  const float* v1_b = (const float*)d_in[10];
    const float* o1_w  = (const float*)d_in[11]; const float* o1_b = (const float*)d_in[12];
    const float* q2_w  = (const float*)d_in[13]; const float* q2_b = (const float*)d_in[14];
    const float* k2_w  = (const float*)d_in[15]; const float* k2_b = (const float*)d_in[16];
    const float* v2_w  = (const float*)d_in[17]; const float* v2_b = (const float*)d_in[18];
    const float* o2_w  = (const float*)d_in[19]; const float* o2_b = (const float*)d_in[20];
    const float* gwih  = (const float*)d_in[21]; const float* gwhh = (const float*)d_in[22];
    const float* gbih  = (const float*)d_in[23]; const float* gbhh = (const float*)d_in[24];
    const float* lin_w = (const float*)d_in[25]; const float* lin_b = (const float*)d_in[26];

    const int bs = in_sizes[0] / (64 * 64);           // 4096
    float* out_qs = (float*)d_out;
    float* out_h3 = out_qs + (size_t)bs * 64 * 20;
    u16* W16 = (u16*)d_ws;

    hipLaunchKernelGGL(convert_weights, dim3((W16_TOTAL + 255) / 256), dim3(256), 0, stream,
                       enc_w, q1_w, k1_w, v1_w, o1_w, q2_w, k2_w, v2_w, o2_w,
                       gwih, gwhh, lin_w, W16);
    hipLaunchKernelGGL(drgn_mfma, dim3(bs / 2), dim3(512), 0, stream,
                       x, mask, h0, W16, enc_b,
                       q1_b, k1_b, v1_b, o1_b, q2_b, k2_b, v2_b, o2_b,
                       gbih, gbhh, lin_b, out_qs, out_h3);
}

// Round 3
// 451.087 us; speedup vs baseline: 12.9958x; 1.3322x over previous
//
#include <hip/hip_runtime.h>
#include <hip/hip_bf16.h>

typedef unsigned int u32;
typedef unsigned short u16;
typedef unsigned long long u64;

using bf16x8 = __attribute__((ext_vector_type(8))) short;
using f32x4  = __attribute__((ext_vector_type(4))) float;

#define NUNITS 31
#define WS_BIAS_OFF (NUNITS*8192)
#define NBIAS 1952

__device__ __forceinline__ u32 pk2(float a, float b){
    __hip_bfloat162 h = __float22bfloat162_rn(make_float2(a, b));
    union { __hip_bfloat162 h2; u32 u; } cv; cv.h2 = h; return cv.u;
}
__device__ __forceinline__ float b2f(u16 v){ return __uint_as_float(((u32)v) << 16); }
__device__ __forceinline__ int swch(int chunk, int key){ return (chunk & ~7) | ((chunk ^ key) & 7); }

// ---------------- weight pre-conversion: f32 -> bf16, unit-major, pre-swizzled ----------------
__global__ __launch_bounds__(256) void convert_weights(
    const float* __restrict__ enc_w,
    const float* __restrict__ q1, const float* __restrict__ k1,
    const float* __restrict__ v1, const float* __restrict__ o1,
    const float* __restrict__ q2, const float* __restrict__ k2,
    const float* __restrict__ v2, const float* __restrict__ o2,
    const float* __restrict__ gih, const float* __restrict__ ghh,
    const float* __restrict__ lin,
    const float* __restrict__ enc_b,
    const float* __restrict__ q1b, const float* __restrict__ k1b,
    const float* __restrict__ v1b, const float* __restrict__ o1b,
    const float* __restrict__ q2b, const float* __restrict__ k2b,
    const float* __restrict__ v2b, const float* __restrict__ o2b,
    const float* __restrict__ gbih, const float* __restrict__ gbhh,
    const float* __restrict__ linb,
    u16* __restrict__ dst)
{
    int idx = blockIdx.x*256 + threadIdx.x;
    if (idx < NUNITS*8192){
        int u = idx >> 13, rem = idx & 8191;
        int row = rem >> 6, ci = rem & 63;
        int p = ci >> 3, e = ci & 7;
        int lc = (((p ^ (row & 7)) & 7) << 3) | e;   // logical col within 64-wide half
        float val;
        if (u == 0){
            val = enc_w[row*64 + lc];
        } else if (u <= 16){
            int v = u - 1; int kh = v & 1;
            const float* s;
            switch (v >> 1){ case 0: s=q1; break; case 1: s=k1; break; case 2: s=v1; break;
                             case 3: s=o1; break; case 4: s=q2; break; case 5: s=k2; break;
                             case 6: s=v2; break; default: s=o2; }
            val = s[row*128 + kh*64 + lc];
        } else if (u <= 28){
            int v = u - 17; int kh = v & 1; int gate = v >> 2;
            const float* s = ((v >> 1) & 1) ? ghh : gih;
            val = s[(gate*128 + row)*128 + kh*64 + lc];
        } else {
            int kh = u - 29;
            val = (row < 20) ? lin[row*128 + kh*64 + lc] : 0.f;
        }
        __hip_bfloat16 hv = __float2bfloat16(val);
        union { __hip_bfloat16 h; u16 us; } cv; cv.h = hv;
        dst[idx] = cv.us;
    } else if (idx < NUNITS*8192 + NBIAS){
        int i = idx - NUNITS*8192;
        float val;
        if      (i < 128)  val = enc_b[i];
        else if (i < 256)  val = q1b[i-128];
        else if (i < 384)  val = k1b[i-256];
        else if (i < 512)  val = v1b[i-384];
        else if (i < 640)  val = o1b[i-512];
        else if (i < 768)  val = q2b[i-640];
        else if (i < 896)  val = k2b[i-768];
        else if (i < 1024) val = v2b[i-896];
        else if (i < 1152) val = o2b[i-1024];
        else if (i < 1536) val = gbih[i-1152];
        else if (i < 1920) val = gbhh[i-1536];
        else if (i < 1940) val = linb[i-1920];
        else               val = 0.f;
        ((float*)(dst + NUNITS*8192))[i] = val;
    }
}

// ---------------- pipeline primitives ----------------
#define BARX() do{ asm volatile("s_waitcnt lgkmcnt(0)" ::: "memory"); \
                   __builtin_amdgcn_s_barrier(); \
                   asm volatile("" ::: "memory"); }while(0)
#define WAITV(N) asm volatile("s_waitcnt vmcnt(" #N ")" ::: "memory")

__device__ __forceinline__ void issue_unit(const u16* Wu, u16* WBs, int u, int w, int lane){
    u16* slot = WBs + (u % 3) * 8192;
    const u16* src = Wu + u * 8192;
    const int s0 = w * 2;
    #pragma unroll
    for (int t = 0; t < 2; t++){
        const u16* gp = src + (s0 + t)*512 + lane*8;
        u16* lp = slot + (s0 + t)*512;
        __builtin_amdgcn_global_load_lds(
            (const __attribute__((address_space(1))) void*)gp,
            (__attribute__((address_space(3))) void*)lp,
            16, 0, 0);
    }
}

#define SLOTR(U) (WBs + ((U) % 3) * 8192)
#define RND(UISS) do{ BARX(); issue_unit(Wu, WBs, (UISS), w, lane); WAITV(4); BARX(); }while(0)
#define RNDL2()   do{ BARX(); WAITV(2); BARX(); }while(0)
#define RNDL0()   do{ BARX(); WAITV(0); BARX(); }while(0)

template<int MT,int NT>
__device__ __forceinline__ void zacc(f32x4 (&a)[MT][NT]){
    #pragma unroll
    for (int i=0;i<MT;i++)
        #pragma unroll
        for (int j=0;j<NT;j++) a[i][j] = (f32x4){0.f,0.f,0.f,0.f};
}

// Y = X @ W^T : mfma(a=W-frag, b=X-frag) -> D[oc][row]; lane c = row, regs = oc
template<int MT,int NT>
__device__ __forceinline__ void wgemm_half(const u16* Wb, const u16* X, int cb,
                                           int mt0, int nt0, int c, int g,
                                           f32x4 (&acc)[MT][NT]){
    #pragma unroll
    for (int kk = 0; kk < 2; kk++){
        const int pw = (kk*4 + g) ^ (c & 7);
        bf16x8 a[MT];
        #pragma unroll
        for (int i = 0; i < MT; i++)
            a[i] = *(const bf16x8*)(Wb + ((mt0+i)*16 + c)*64 + pw*8);
        #pragma unroll
        for (int j = 0; j < NT; j++){
            bf16x8 b = *(const bf16x8*)(X + ((nt0+j)*16 + c)*128 + (cb + pw)*8);
            #pragma unroll
            for (int i = 0; i < MT; i++)
                acc[i][j] = __builtin_amdgcn_mfma_f32_16x16x32_bf16(a[i], b, acc[i][j], 0,0,0);
        }
    }
}

// V-GEMM: mfma(a=X-frag, b=W-frag) -> D[token][vcol]; lane c = vcol, regs = token
template<int MT,int NT>
__device__ __forceinline__ void vgemm_half(const u16* Wb, const u16* X, int cb,
                                           int mt0, int nt0, int c, int g,
                                           f32x4 (&acc)[MT][NT]){
    #pragma unroll
    for (int kk = 0; kk < 2; kk++){
        const int pw = (kk*4 + g) ^ (c & 7);
        bf16x8 a[MT];
        #pragma unroll
        for (int i = 0; i < MT; i++)
            a[i] = *(const bf16x8*)(X + ((mt0+i)*16 + c)*128 + (cb + pw)*8);
        #pragma unroll
        for (int j = 0; j < NT; j++){
            bf16x8 b = *(const bf16x8*)(Wb + ((nt0+j)*16 + c)*64 + pw*8);
            #pragma unroll
            for (int i = 0; i < MT; i++)
                acc[i][j] = __builtin_amdgcn_mfma_f32_16x16x32_bf16(a[i], b, acc[i][j], 0,0,0);
        }
    }
}

template<int MT,int NT,bool RELU>
__device__ __forceinline__ void epi_w(f32x4 (&acc)[MT][NT], const float* BL, int boff,
                                      u16* dst, int mt0, int nt0, int c, int g){
    const int key = c & 7;
    #pragma unroll
    for (int i=0;i<MT;i++){
        const int col = (mt0+i)*16 + g*4;
        float4 bv = *(const float4*)(BL + boff + col);
        const int coff = swch(col>>3, key)*8 + (col&7);
        #pragma unroll
        for (int j=0;j<NT;j++){
            int row = (nt0+j)*16 + c;
            float v0 = acc[i][j][0]+bv.x, v1 = acc[i][j][1]+bv.y;
            float v2 = acc[i][j][2]+bv.z, v3 = acc[i][j][3]+bv.w;
            if (RELU){ v0=fmaxf(v0,0.f); v1=fmaxf(v1,0.f); v2=fmaxf(v2,0.f); v3=fmaxf(v3,0.f); }
            uint2 o; o.x = pk2(v0,v1); o.y = pk2(v2,v3);
            *(uint2*)(dst + row*128 + coff) = o;
        }
    }
}

// ---------------- main fused kernel: 2 batch items / block, 512 threads ----------------
__global__ __launch_bounds__(512) void drgn_pipe(
    const float* __restrict__ x, const int* __restrict__ maskg,
    const float* __restrict__ h0, const u16* __restrict__ W16,
    float* __restrict__ out_qs, float* __restrict__ out_h3)
{
    __shared__ u16 ACT0[128*128];      // 32KB: layer act / V^T / h2 / h3
    __shared__ u16 QX[128*128];        // 32KB: x-in / Q / X1 / h0-bf16
    __shared__ u16 KP[128*128];        // 32KB: K
    __shared__ u16 WBs[3*8192];        // 48KB: weight ring (3 x 16KB)
    __shared__ u64 MrowS[128];
    __shared__ float BLDS[NBIAS];

    const int tid = threadIdx.x;
    const int w = tid >> 6, lane = tid & 63;
    const int c = lane & 15, g = lane >> 4;
    const int key = c & 7;
    const size_t rowbase = (size_t)blockIdx.x * 128;
    const u16* Wu = W16;
    const float* wsb = (const float*)(W16 + WS_BIAS_OFF);
    const int mt0 = (w>>1)*2, nt0 = (w&1)*4;

    // ---- prologue: mask bits, x -> bf16 LDS, biases ----
    #pragma unroll 4
    for (int rr2 = 0; rr2 < 16; rr2++){
        int row = w*16 + rr2;
        int mv = maskg[(rowbase + row)*64 + lane];
        u64 bits = __ballot(mv != 0);
        if (lane == 0) MrowS[row] = bits;
    }
    for (int chv = tid; chv < 1024; chv += 512){
        int row = chv >> 3, p = chv & 7;
        int lc = (p ^ (row & 7)) & 7;
        const float* sp = x + (rowbase + row)*64 + lc*8;
        float4 f0 = *(const float4*)sp;
        float4 f1 = *(const float4*)(sp + 4);
        uint4 o; o.x = pk2(f0.x,f0.y); o.y = pk2(f0.z,f0.w);
        o.z = pk2(f1.x,f1.y); o.w = pk2(f1.z,f1.w);
        *(uint4*)(QX + row*128 + p*8) = o;
    }
    for (int i = tid; i < NBIAS; i += 512) BLDS[i] = wsb[i];

    asm volatile("s_waitcnt vmcnt(0)" ::: "memory");
    issue_unit(Wu, WBs, 0, w, lane);
    issue_unit(Wu, WBs, 1, w, lane);

    f32x4 acc[2][4];

    // ---- encoder (u0): ACT0 = relu(Xin @ enc^T + b) ----
    RND(2);
    zacc(acc);
    wgemm_half<2,4>(SLOTR(0), QX, 0, mt0, nt0, c, g, acc);
    epi_w<2,4,true>(acc, BLDS, 0, ACT0, mt0, nt0, c, g);

    // ---- two MHA layers ----
    for (int layer = 0; layer < 2; layer++){
        const int ub = 1 + layer*8;
        const int bb = 128 + layer*512;
        // Q (u_b, u_b+1)
        RND(ub+2); zacc(acc); wgemm_half<2,4>(SLOTR(ub+0), ACT0, 0, mt0,nt0,c,g,acc);
        RND(ub+3); wgemm_half<2,4>(SLOTR(ub+1), ACT0, 8, mt0,nt0,c,g,acc);
        epi_w<2,4,true>(acc, BLDS, bb, QX, mt0,nt0,c,g);
        // K
        RND(ub+4); zacc(acc); wgemm_half<2,4>(SLOTR(ub+2), ACT0, 0, mt0,nt0,c,g,acc);
        RND(ub+5); wgemm_half<2,4>(SLOTR(ub+3), ACT0, 8, mt0,nt0,c,g,acc);
        epi_w<2,4,true>(acc, BLDS, bb+128, KP, mt0,nt0,c,g);
        // V (acc only)
        RND(ub+6); zacc(acc); vgemm_half<2,4>(SLOTR(ub+4), ACT0, 0, mt0,nt0,c,g,acc);
        RND(ub+7); vgemm_half<2,4>(SLOTR(ub+5), ACT0, 8, mt0,nt0,c,g,acc);

        // ---- attention ----
        BARX();   // all ACT0 (layer input) reads done -> safe to overwrite with V^T
        {   // V^T epilogue -> ACT0, token positions pi-permuted
            #pragma unroll
            for (int j = 0; j < 4; j++){
                int vrow = (nt0+j)*16 + c;
                float bv = BLDS[bb + 256 + vrow];
                #pragma unroll
                for (int i = 0; i < 2; i++){
                    int mt = mt0 + i;
                    int pos = (mt>>2)*64 + ((mt&3)>>1)*32 + g*8 + (mt&1)*4;
                    float v0 = fmaxf(acc[i][j][0]+bv, 0.f);
                    float v1 = fmaxf(acc[i][j][1]+bv, 0.f);
                    float v2 = fmaxf(acc[i][j][2]+bv, 0.f);
                    float v3 = fmaxf(acc[i][j][3]+bv, 0.f);
                    uint2 o; o.x = pk2(v0,v1); o.y = pk2(v2,v3);
                    *(uint2*)(ACT0 + vrow*128 + swch(pos>>3, key)*8 + (pos&7)) = o;
                }
            }
        }
        const int ab = w >> 2, h = w & 3;   // wave = (batch-half, head)
        f32x4 sc[4][4];
        {   // scores: mfma(K,Q) -> lane c = qrow, regs = kcol
            bf16x8 kf[4];
            #pragma unroll
            for (int kt=0;kt<4;kt++)
                kf[kt] = *(const bf16x8*)(KP + (ab*64+kt*16+c)*128 + swch(h*4+g, key)*8);
            #pragma unroll
            for (int qt=0;qt<4;qt++){
                bf16x8 qf = *(const bf16x8*)(QX + (ab*64+qt*16+c)*128 + swch(h*4+g, key)*8);
                #pragma unroll
                for (int kt=0;kt<4;kt++){
                    f32x4 z4 = (f32x4){0.f,0.f,0.f,0.f};
                    sc[qt][kt] = __builtin_amdgcn_mfma_f32_16x16x32_bf16(kf[kt], qf, z4, 0,0,0);
                }
            }
        }
        BARX();   // Q/K reads + V^T writes complete
        {   // in-register masked softmax + PV (P never touches LDS)
            u32 pp[4][4][2];
            #pragma unroll
            for (int qt=0;qt<4;qt++){
                u64 mb = MrowS[ab*64 + qt*16 + c];
                float mx = -1e30f;
                #pragma unroll
                for (int kt=0;kt<4;kt++)
                    #pragma unroll
                    for (int r=0;r<4;r++){
                        float s = sc[qt][kt][r] * 0.17677669529663687f;
                        s = ((mb >> (kt*16 + g*4 + r)) & 1ull) ? s : -1e30f;
                        sc[qt][kt][r] = s;
                        mx = fmaxf(mx, s);
                    }
                mx = fmaxf(mx, __shfl_xor(mx, 16));
                mx = fmaxf(mx, __shfl_xor(mx, 32));
                float sum = 0.f;
                #pragma unroll
                for (int kt=0;kt<4;kt++)
                    #pragma unroll
                    for (int r=0;r<4;r++){
                        float e = __expf(sc[qt][kt][r] - mx);
                        sc[qt][kt][r] = e; sum += e;
                    }
                sum += __shfl_xor(sum, 16);
                sum += __shfl_xor(sum, 32);
                float inv = 1.f / sum;
                #pragma unroll
                for (int kt=0;kt<4;kt++){
                    pp[qt][kt][0] = pk2(sc[qt][kt][0]*inv, sc[qt][kt][1]*inv);
                    pp[qt][kt][1] = pk2(sc[qt][kt][2]*inv, sc[qt][kt][3]*inv);
                }
            }
            // PV: mfma(V^T, P) -> lane c = qrow, regs = d; write X1 into QX
            #pragma unroll
            for (int dt=0; dt<2; dt++){
                f32x4 pa[4];
                #pragma unroll
                for (int qt=0;qt<4;qt++) pa[qt] = (f32x4){0.f,0.f,0.f,0.f};
                #pragma unroll
                for (int kk=0; kk<2; kk++){
                    bf16x8 vt = *(const bf16x8*)(ACT0 + (h*32+dt*16+c)*128 + (ab*8 + ((kk*4+g)^key))*8);
                    #pragma unroll
                    for (int qt=0;qt<4;qt++){
                        union { u32 u4[4]; bf16x8 v8; } bbv;
                        bbv.u4[0]=pp[qt][kk*2][0];   bbv.u4[1]=pp[qt][kk*2][1];
                        bbv.u4[2]=pp[qt][kk*2+1][0]; bbv.u4[3]=pp[qt][kk*2+1][1];
                        pa[qt] = __builtin_amdgcn_mfma_f32_16x16x32_bf16(vt, bbv.v8, pa[qt], 0,0,0);
                    }
                }
                #pragma unroll
                for (int qt=0;qt<4;qt++){
                    int col = h*32 + dt*16 + g*4;
                    uint2 o; o.x = pk2(pa[qt][0], pa[qt][1]); o.y = pk2(pa[qt][2], pa[qt][3]);
                    *(uint2*)(QX + (ab*64+qt*16+c)*128 + swch(col>>3, key)*8 + (col&7)) = o;
                }
            }
        }
        // O-projection: ACT0 = relu(X1 @ Wo^T + b)
        RND(ub+8); zacc(acc); wgemm_half<2,4>(SLOTR(ub+6), QX, 0, mt0,nt0,c,g,acc);
        RND(ub+9); wgemm_half<2,4>(SLOTR(ub+7), QX, 8, mt0,nt0,c,g,acc);
        epi_w<2,4,true>(acc, BLDS, bb+384, ACT0, mt0,nt0,c,g);
    }

    // ---- GRU ----
    f32x4 aI[2][4], aH[2][4];
    float rrA[2][4][4], zzA[2][4][4];
    for (int gate = 0; gate < 3; gate++){
        const int u = 17 + gate*4;
        RND(u+2); zacc(aI); wgemm_half<2,4>(SLOTR(u+0), ACT0, 0, mt0,nt0,c,g,aI);
        if (gate == 0){
            // stage h0 -> QX as bf16 (QX free after o-proj L2)
            for (int chv = tid; chv < 2048; chv += 512){
                int row = chv >> 4, p = chv & 15;
                int lc2 = (p & 8) | ((p ^ (row & 7)) & 7);
                const float* sp = h0 + (rowbase + row)*128 + lc2*8;
                float4 f0 = *(const float4*)sp;
                float4 f1 = *(const float4*)(sp + 4);
                uint4 o; o.x = pk2(f0.x,f0.y); o.y = pk2(f0.z,f0.w);
                o.z = pk2(f1.x,f1.y); o.w = pk2(f1.z,f1.w);
                *(uint4*)(QX + row*128 + p*8) = o;
            }
        }
        RND(u+3); wgemm_half<2,4>(SLOTR(u+1), ACT0, 8, mt0,nt0,c,g,aI);
        RND(u+4); zacc(aH); wgemm_half<2,4>(SLOTR(u+2), QX, 0, mt0,nt0,c,g,aH);
        RND(u+5); wgemm_half<2,4>(SLOTR(u+3), QX, 8, mt0,nt0,c,g,aH);
        if (gate < 2){
            #pragma unroll
            for (int i=0;i<2;i++){
                int col0 = (mt0+i)*16 + g*4;
                float4 bi = *(const float4*)(BLDS + 1152 + gate*128 + col0);
                float4 bh = *(const float4*)(BLDS + 1536 + gate*128 + col0);
                #pragma unroll
                for (int j=0;j<4;j++)
                    #pragma unroll
                    for (int r=0;r<4;r++){
                        float v = aI[i][j][r] + (&bi.x)[r] + aH[i][j][r] + (&bh.x)[r];
                        float s = 1.f/(1.f+__expf(-v));
                        if (gate==0) rrA[i][j][r]=s; else zzA[i][j][r]=s;
                    }
            }
        } else {
            #pragma unroll
            for (int i=0;i<2;i++){
                int col0 = (mt0+i)*16 + g*4;
                float4 bi = *(const float4*)(BLDS + 1152 + 256 + col0);
                float4 bh = *(const float4*)(BLDS + 1536 + 256 + col0);
                int coff = swch(col0>>3, key)*8 + (col0&7);
                #pragma unroll
                for (int j=0;j<4;j++){
                    int row = (nt0+j)*16 + c;
                    uint2 hv = *(const uint2*)(QX + row*128 + coff);
                    float h0v[4] = { b2f((u16)(hv.x & 0xffffu)), b2f((u16)(hv.x >> 16)),
                                     b2f((u16)(hv.y & 0xffffu)), b2f((u16)(hv.y >> 16)) };
                    float h3v[4];
                    #pragma unroll
                    for (int r=0;r<4;r++){
                        float xn = aI[i][j][r] + (&bi.x)[r] + rrA[i][j][r]*(aH[i][j][r] + (&bh.x)[r]);
                        float e2 = __expf(-2.f*fabsf(xn));
                        float th = (1.f - e2)/(1.f + e2);
                        th = (xn >= 0.f) ? th : -th;
                        float zv = zzA[i][j][r];
                        h3v[r] = (1.f - zv)*th + zv*h0v[r];
                    }
                    uint2 o; o.x = pk2(h3v[0],h3v[1]); o.y = pk2(h3v[2],h3v[3]);
                    *(uint2*)(ACT0 + row*128 + coff) = o;   // h3 -> ACT0
                }
            }
        }
    }

    // ---- final linear (u29,u30) + stores ----
    f32x4 qa[1][2];
    const int mq = w & 1, nq = (w>>1)*2;
    RNDL2(); zacc(qa);
    wgemm_half<1,2>(SLOTR(29), ACT0, 0, mq, nq, c, g, qa);
    RNDL0();
    wgemm_half<1,2>(SLOTR(30), ACT0, 8, mq, nq, c, g, qa);
    if (!(mq == 1 && g > 0)){
        int col0 = mq*16 + g*4;
        float4 lb = *(const float4*)(BLDS + 1920 + col0);
        #pragma unroll
        for (int j=0;j<2;j++){
            int row = (nq+j)*16 + c;
            float4 o; o.x = qa[0][j][0]+lb.x; o.y = qa[0][j][1]+lb.y;
            o.z = qa[0][j][2]+lb.z; o.w = qa[0][j][3]+lb.w;
            *(float4*)(out_qs + (rowbase + row)*20 + col0) = o;
        }
    }
    // h3 -> global f32
    for (int chv = tid; chv < 2048; chv += 512){
        int row = chv >> 4, p = chv & 15;
        int lc2 = (p & 8) | ((p ^ (row & 7)) & 7);
        bf16x8 v = *(const bf16x8*)(ACT0 + row*128 + p*8);
        float* dp = out_h3 + (rowbase + row)*128 + lc2*8;
        float4 o0, o1;
        o0.x = b2f((u16)v[0]); o0.y = b2f((u16)v[1]); o0.z = b2f((u16)v[2]); o0.w = b2f((u16)v[3]);
        o1.x = b2f((u16)v[4]); o1.y = b2f((u16)v[5]); o1.z = b2f((u16)v[6]); o1.w = b2f((u16)v[7]);
        *(float4*)dp = o0; *(float4*)(dp + 4) = o1;
    }
}

extern "C" void kernel_launch(void* const* d_in, const int* in_sizes, int n_in,
                              void* d_out, int out_size, void* d_ws, size_t ws_size,
                              hipStream_t stream) {
    const float* x     = (const float*)d_in[0];
    const int*   mask  = (const int*)  d_in[1];
    const float* h0    = (const float*)d_in[2];
    const float* enc_w = (const float*)d_in[3];
    const float* enc_b = (const float*)d_in[4];
    const float* q1_w  = (const float*)d_in[5];  const float* q1_b = (const float*)d_in[6];
    const float* k1_w  = (const float*)d_in[7];  const float* k1_b = (const float*)d_in[8];
    const float* v1_w  = (const float*)d_in[9];  const float* v1_b = (const float*)d_in[10];
    const float* o1_w  = (const float*)d_in[11]; const float* o1_b = (const float*)d_in[12];
    const float* q2_w  = (const float*)d_in[13]; const float* q2_b = (const float*)d_in[14];
    const float* k2_w  = (const float*)d_in[15]; const float* k2_b = (const float*)d_in[16];
    const float* v2_w  = (const float*)d_in[17]; const float* v2_b = (const float*)d_in[18];
    const float* o2_w  = (const float*)d_in[19]; const float* o2_b = (const float*)d_in[20];
    const float* gwih  = (const float*)d_in[21]; const float* gwhh = (const float*)d_in[22];
    const float* gbih  = (const float*)d_in[23]; const float* gbhh = (const float*)d_in[24];
    const float* lin_w = (const float*)d_in[25]; const float* lin_b = (const float*)d_in[26];

    const int bs = in_sizes[0] / (64 * 64);           // 4096
    float* out_qs = (float*)d_out;
    float* out_h3 = out_qs + (size_t)bs * 64 * 20;
    u16* W16 = (u16*)d_ws;

    const int total = NUNITS*8192 + NBIAS;
    hipLaunchKernelGGL(convert_weights, dim3((total + 255) / 256), dim3(256), 0, stream,
                       enc_w, q1_w, k1_w, v1_w, o1_w, q2_w, k2_w, v2_w, o2_w,
                       gwih, gwhh, lin_w,
                       enc_b, q1_b, k1_b, v1_b, o1_b, q2_b, k2_b, v2_b, o2_b,
                       gbih, gbhh, lin_b, W16);
    hipLaunchKernelGGL(drgn_pipe, dim3(bs / 2), dim3(512), 0, stream,
                       x, mask, h0, W16, out_qs, out_h3);
}